// Round 17
// baseline (253.612 us; speedup 1.0000x reference)
//
#include <hip/hip_runtime.h>
#include <hip/hip_fp16.h>
#include <math.h>

#define PI_F      3.14159265358979323846f
#define TWO_PI_F  6.28318530717958647692f
#define PI4_F     0.78539816339744830962f   // pi/4 == ROT_SCALE == 2pi/8

typedef _Float16 f16x8 __attribute__((ext_vector_type(8)));
typedef float    f32x4 __attribute__((ext_vector_type(4)));

__device__ __forceinline__ float sgn(float t) {
    return (t > 0.f) ? 1.f : ((t < 0.f) ? -1.f : 0.f);
}

__device__ __forceinline__ float b2(float x) {
    float a = x - 0.5f;
    float b = x - 1.5f;
    float c = 1.f + 2.f * x;
    float d = 3.f + 2.f * x;
    return (-3.f * a * a * sgn(0.5f - x)
            + b * b * sgn(1.5f - x)
            - 0.75f * c * c * sgn(0.5f + x)
            + 0.25f * d * d * sgn(1.5f + x)) * 0.25f;
}

// ks_h[t][O][I] fp16.  t = dx*5+dy, O = r0*8+o, I = i*8+r
__global__ void build_ks_kernel(const float* __restrict__ w, __half* __restrict__ ksh) {
    int g = blockIdx.x * 256 + threadIdx.x;
    if (g >= 64 * 32 * 25) return;
    int O = g & 63;
    int rest = g >> 6;
    int t = rest % 25;
    int I = rest / 25;
    int r0 = O >> 3, o = O & 7;
    int i = I >> 3, r = I & 7;
    int x = t / 5, y = t % 5;

    float theta = -(float)r0 * PI4_F;
    float cth = cosf(theta), sth = sinf(theta);
    float fx = (float)(x - 2), fy = (float)(y - 2);
    float xc = fx * cth - fy * sth;
    float yc = fx * sth + fy * cth;

    float rotv[8];
    float rs = (float)r * PI4_F + theta;
    #pragma unroll
    for (int mr = 0; mr < 8; ++mr) {
        float v = (float)mr * PI4_F - rs + PI_F;
        float md = fmodf(v, TWO_PI_F);
        if (md < 0.f) md += TWO_PI_F;
        rotv[mr] = b2((md - PI_F) / PI4_F);
    }

    float sum = 0.f;
    for (int mx = 0; mx < 25; ++mx) {
        float cx = (float)(mx / 5 - 2);
        float cy = (float)(mx % 5 - 2);
        float bx = b2(cx - xc) * b2(cy - yc);
        if (bx != 0.f) {
            const float* wp = w + (size_t)(i * 200 + mx * 8) * 8 + o;
            #pragma unroll
            for (int mr = 0; mr < 8; ++mr)
                sum = fmaf(bx * rotv[mr], wp[mr * 8], sum);
        }
    }
    ksh[(size_t)(t * 64 + O) * 32 + I] = __float2half(sum);
}

// Producer-consumer wave-specialized implicit-GEMM conv.
// 256 blocks (1/CU), 512 threads = 8 waves. Block owns 4 tiles of 16h x 32w
// (same batch & h-strip, w advancing). LDS double buffer xt[2][4 slot][720 px]
// uint4 stride 721 (92.3 KB -> 1 block/CU).
//   waves 0-3 (consumers): tile s taps+stores; acc[8][4], 32 MFMA/tap, NO
//     stage registers.
//   waves 4-7 (producers): stage tile s+1 (f32 load -> cvt fp16 -> ds_write)
//     into the other buffer; NO accumulators.
// Each SIMD hosts 1 consumer + 1 producer -> MFMA and stage co-issue (m114).
// One raw s_barrier + lgkmcnt(0) per tile; output stores are never drained
// inside the loop (vmcnt never forced to 0).
__global__ __launch_bounds__(512, 2) void conv_pc_kernel(const float* __restrict__ X,
                                                         const __half* __restrict__ ksh,
                                                         float* __restrict__ out) {
    __shared__ uint4 xt[2][4 * 721];    // 2 x 46,144 B

    int bid = blockIdx.x;
    int b   = bid >> 5;               // 8 batches, b-major
    int rem = bid & 31;
    int h0  = (rem >> 1) << 4;        // 16 h-strips of 16
    int wg  = (rem & 1) << 2;         // w-strip group: strips wg..wg+3
    int tid = threadIdx.x;
    int wave = tid >> 6, lane = tid & 63;

    const float* Xb = X + (size_t)b * 32 * 65536;

    // ---- prologue: all 512 threads stage tile 0 -> xt[0] ----
    {
        int w0n = wg << 5;
        for (int lin = tid; lin < 2880; lin += 512) {
            int slot = lin / 720;
            int p    = lin - slot * 720;
            int r = p / 36, c = p - (p / 36) * 36;
            int gh = h0 + r - 2, gw = w0n + c - 2;
            union { __half hh[8]; uint4 u; } q;
            if ((unsigned)gh < 256u && (unsigned)gw < 256u) {
                const float* src = Xb + (size_t)slot * 8 * 65536 + gh * 256 + gw;
                #pragma unroll
                for (int j = 0; j < 8; ++j) q.hh[j] = __float2half(src[j * 65536]);
            } else {
                q.u = make_uint4(0u, 0u, 0u, 0u);
            }
            xt[0][slot * 721 + p] = q.u;
        }
    }
    asm volatile("s_waitcnt lgkmcnt(0)" ::: "memory");
    __builtin_amdgcn_s_barrier();

    if (wave < 4) {
        // ================= consumers =================
        int lO = lane & 15, ks4 = lane >> 4;
        int bidx = lO * 4 + ks4;
        const uint4* ksq = (const uint4*)ksh;

        int baseA[8];
        #pragma unroll
        for (int m = 0; m < 8; ++m)
            baseA[m] = 721 * ks4 + (wave * 4 + (m >> 1)) * 36 + (m & 1) * 16 + lO;

        #pragma unroll 1
        for (int s = 0; s < 4; ++s) {
            const uint4* cbuf = &xt[s & 1][0];
            int w0s = (wg + s) << 5;

            f32x4 acc[8][4] = {};
            f16x8 Bf[2][4];
            #pragma unroll
            for (int n = 0; n < 4; ++n)
                Bf[0][n] = __builtin_bit_cast(f16x8, ksq[n * 64 + bidx]);

            #pragma unroll
            for (int t = 0; t < 25; ++t) {
                const int cur = t & 1, nxt = cur ^ 1;
                const int aoff = (t / 5) * 36 + (t % 5);

                f16x8 Af[8];
                #pragma unroll
                for (int m = 0; m < 8; ++m)
                    Af[m] = __builtin_bit_cast(f16x8, cbuf[baseA[m] + aoff]);

                if (t < 24) {
                    #pragma unroll
                    for (int n = 0; n < 4; ++n)
                        Bf[nxt][n] = __builtin_bit_cast(f16x8, ksq[(t + 1) * 256 + n * 64 + bidx]);
                }

                #pragma unroll
                for (int m = 0; m < 8; ++m) {
                    #pragma unroll
                    for (int n = 0; n < 4; ++n)
                        acc[m][n] = __builtin_amdgcn_mfma_f32_16x16x32_f16(Af[m], Bf[cur][n], acc[m][n], 0, 0, 0);
                }
            }

            // stores: out[b][O&7][O>>3][h][w] * (2pi/8); full 128-B lines
            #pragma unroll
            for (int m = 0; m < 8; ++m) {
                int gh  = h0 + wave * 4 + (m >> 1);
                int gwb = w0s + (m & 1) * 16 + ks4 * 4;
                #pragma unroll
                for (int n = 0; n < 4; ++n) {
                    int O = n * 16 + lO;
                    float* op = out + (((size_t)(b * 8 + (O & 7)) * 8 + (O >> 3)) << 16)
                                    + gh * 256 + gwb;
                    *(f32x4*)op = acc[m][n] * PI4_F;
                }
            }

            asm volatile("s_waitcnt lgkmcnt(0)" ::: "memory");
            __builtin_amdgcn_s_barrier();
        }
    } else {
        // ================= producers =================
        int ptid = tid - 256;   // 0..255
        #pragma unroll 1
        for (int s = 0; s < 4; ++s) {
            if (s < 3) {
                uint4* nbuf = &xt[(s + 1) & 1][0];
                int w0n = (wg + s + 1) << 5;
                for (int lin = ptid; lin < 2880; lin += 256) {
                    int slot = lin / 720;
                    int p    = lin - slot * 720;
                    int r = p / 36, c = p - (p / 36) * 36;
                    int gh = h0 + r - 2, gw = w0n + c - 2;
                    union { __half hh[8]; uint4 u; } q;
                    if ((unsigned)gh < 256u && (unsigned)gw < 256u) {
                        const float* src = Xb + (size_t)slot * 8 * 65536 + gh * 256 + gw;
                        #pragma unroll
                        for (int j = 0; j < 8; ++j) q.hh[j] = __float2half(src[j * 65536]);
                    } else {
                        q.u = make_uint4(0u, 0u, 0u, 0u);
                    }
                    nbuf[slot * 721 + p] = q.u;
                }
            }
            asm volatile("s_waitcnt lgkmcnt(0)" ::: "memory");
            __builtin_amdgcn_s_barrier();
        }
    }
}

extern "C" void kernel_launch(void* const* d_in, const int* in_sizes, int n_in,
                              void* d_out, int out_size, void* d_ws, size_t ws_size,
                              hipStream_t stream) {
    const float* X = (const float*)d_in[0];       // (8, 4, 8, 256, 256) f32
    const float* w = (const float*)d_in[1];       // (4, 200, 8) f32
    float* outp = (float*)d_out;                  // (8, 8, 8, 256, 256) f32
    __half* ksh = (__half*)d_ws;                  // 102.4 KB

    build_ks_kernel<<<200, 256, 0, stream>>>(w, ksh);
    conv_pc_kernel<<<256, 512, 0, stream>>>(X, ksh, outp);
}

// Round 18
// 99.850 us; speedup vs baseline: 2.5399x; 2.5399x over previous
//
#include <hip/hip_runtime.h>
#include <hip/hip_fp16.h>
#include <math.h>

#define PI_F      3.14159265358979323846f
#define TWO_PI_F  6.28318530717958647692f
#define PI4_F     0.78539816339744830962f   // pi/4 == ROT_SCALE == 2pi/8

typedef _Float16 f16x8 __attribute__((ext_vector_type(8)));
typedef float    f32x4 __attribute__((ext_vector_type(4)));

#define XH_OFF     ((size_t)1 << 20)                  // 1 MB
#define XH_BYTES   ((size_t)8 * 256 * 256 * 32 * 2)   // 33.55 MB

__device__ __forceinline__ float sgn(float t) {
    return (t > 0.f) ? 1.f : ((t < 0.f) ? -1.f : 0.f);
}

__device__ __forceinline__ float b2(float x) {
    float a = x - 0.5f;
    float b = x - 1.5f;
    float c = 1.f + 2.f * x;
    float d = 3.f + 2.f * x;
    return (-3.f * a * a * sgn(0.5f - x)
            + b * b * sgn(1.5f - x)
            - 0.75f * c * c * sgn(0.5f + x)
            + 0.25f * d * d * sgn(1.5f + x)) * 0.25f;
}

// ks_h[t][O][I] fp16.  t = dx*5+dy, O = r0*8+o, I = i*8+r
__global__ void build_ks_kernel(const float* __restrict__ w, __half* __restrict__ ksh) {
    int g = blockIdx.x * 256 + threadIdx.x;
    if (g >= 64 * 32 * 25) return;
    int O = g & 63;
    int rest = g >> 6;
    int t = rest % 25;
    int I = rest / 25;
    int r0 = O >> 3, o = O & 7;
    int i = I >> 3, r = I & 7;
    int x = t / 5, y = t % 5;

    float theta = -(float)r0 * PI4_F;
    float cth = cosf(theta), sth = sinf(theta);
    float fx = (float)(x - 2), fy = (float)(y - 2);
    float xc = fx * cth - fy * sth;
    float yc = fx * sth + fy * cth;

    float rotv[8];
    float rs = (float)r * PI4_F + theta;
    #pragma unroll
    for (int mr = 0; mr < 8; ++mr) {
        float v = (float)mr * PI4_F - rs + PI_F;
        float md = fmodf(v, TWO_PI_F);
        if (md < 0.f) md += TWO_PI_F;
        rotv[mr] = b2((md - PI_F) / PI4_F);
    }

    float sum = 0.f;
    for (int mx = 0; mx < 25; ++mx) {
        float cx = (float)(mx / 5 - 2);
        float cy = (float)(mx % 5 - 2);
        float bx = b2(cx - xc) * b2(cy - yc);
        if (bx != 0.f) {
            const float* wp = w + (size_t)(i * 200 + mx * 8) * 8 + o;
            #pragma unroll
            for (int mr = 0; mr < 8; ++mr)
                sum = fmaf(bx * rotv[mr], wp[mr * 8], sum);
        }
    }
    ksh[(size_t)(t * 64 + O) * 32 + I] = __float2half(sum);
}

// X (b,32ch,256,256) f32  ->  Xh (b,256,256,32ch) fp16.  One block per (b,h).
__global__ __launch_bounds__(256, 4) void hwc_kernel(const float* __restrict__ X,
                                                     __half* __restrict__ Xh) {
    int b = blockIdx.x >> 8;
    int h = blockIdx.x & 255;
    int ww = threadIdx.x;
    const float* Xb = X + ((size_t)b * 32) * 65536 + h * 256 + ww;

    union { __half hh[8]; uint4 u; } pk[4];
    #pragma unroll
    for (int c = 0; c < 32; ++c)
        pk[c >> 3].hh[c & 7] = __float2half(Xb[(size_t)c * 65536]);

    uint4* dst = (uint4*)(Xh + ((size_t)(b * 65536 + h * 256 + ww)) * 32);
    #pragma unroll
    for (int kk = 0; kk < 4; ++kk) dst[kk] = pk[kk].u;
}

// Implicit-GEMM conv sized for 4 co-resident blocks/CU (de-phased overlap).
// Block = 256 threads (4 waves), tile 8h x 32w px, all 64 O.
// LDS xt[slot(4 k-planes)][432 px (12x36 halo)] uint4, stride 433 (27.7 KB):
//   4 blocks/CU by LDS (110.8 KB) and by registers (r9-proven shape:
//   acc[4][4] = 64 AGPR + ~64 VGPR = 128 unified -> 4 waves/SIMD).
// Independent small blocks drift out of phase across 8 grid rounds, so one
// block's stage/store HBM bursts overlap another's MFMA (m97/m114 regime) —
// the overlap every monolithic phase-locked variant (r9/r13-r17) lacked.
// Wave owns 2 h-rows = 4 M-tiles x 4 N-tiles, 16 MFMA/tap; stage is cheap
// uint4 copies from the fp16 HWC pre-pass (keeps VGPR at the r9 level).
__global__ __launch_bounds__(256, 4) void conv_hwc_kernel(const __half* __restrict__ Xh,
                                                          const __half* __restrict__ ksh,
                                                          float* __restrict__ out) {
    __shared__ uint4 xt[4 * 433];    // 27,712 B

    int bid = blockIdx.x;
    int b   = bid >> 8;              // 8 batches, b-major
    int rem = bid & 255;             // 256 tiles/batch
    int h0  = (rem >> 3) << 3;       // 32 h-strips of 8
    int w0  = (rem & 7) << 5;        // 8 w-strips of 32
    int tid = threadIdx.x;

    const char* Xb = (const char*)Xh + (size_t)b * ((size_t)65536 * 64);

    // ---- stage 432 px * 64 B (uint4 copies, register-cheap) ----
    for (int p = tid; p < 432; p += 256) {
        int r = p / 36, c = p - (p / 36) * 36;
        int gh = h0 + r - 2;
        int gw = w0 + c - 2;
        uint4 v0 = make_uint4(0u, 0u, 0u, 0u), v1 = v0, v2 = v0, v3 = v0;
        if ((unsigned)gh < 256u && (unsigned)gw < 256u) {
            const uint4* s = (const uint4*)(Xb + ((size_t)(gh * 256 + gw)) * 64);
            v0 = s[0]; v1 = s[1]; v2 = s[2]; v3 = s[3];
        }
        xt[0 * 433 + p] = v0;
        xt[1 * 433 + p] = v1;
        xt[2 * 433 + p] = v2;
        xt[3 * 433 + p] = v3;
    }
    __syncthreads();

    int wave = tid >> 6, lane = tid & 63;
    int lO = lane & 15, ks4 = lane >> 4;
    int bidx = lO * 4 + ks4;
    const uint4* ksq = (const uint4*)ksh;

    f32x4 acc[4][4] = {};
    int baseA[4];
    #pragma unroll
    for (int m = 0; m < 4; ++m)
        baseA[m] = 433 * ks4 + (wave * 2 + (m >> 1)) * 36 + (m & 1) * 16 + lO;

    // ---- 25-tap loop: fresh A reads, 1-deep B prefetch double-buffer ----
    f16x8 Bf[2][4];
    #pragma unroll
    for (int n = 0; n < 4; ++n)
        Bf[0][n] = __builtin_bit_cast(f16x8, ksq[n * 64 + bidx]);

    #pragma unroll
    for (int t = 0; t < 25; ++t) {
        const int cur = t & 1, nxt = cur ^ 1;
        const int aoff = (t / 5) * 36 + (t % 5);

        f16x8 Af[4];
        #pragma unroll
        for (int m = 0; m < 4; ++m)
            Af[m] = __builtin_bit_cast(f16x8, xt[baseA[m] + aoff]);

        if (t < 24) {
            const int t1 = t + 1;
            #pragma unroll
            for (int n = 0; n < 4; ++n)
                Bf[nxt][n] = __builtin_bit_cast(f16x8, ksq[t1 * 256 + n * 64 + bidx]);
        }

        __builtin_amdgcn_s_setprio(1);
        #pragma unroll
        for (int m = 0; m < 4; ++m) {
            #pragma unroll
            for (int n = 0; n < 4; ++n)
                acc[m][n] = __builtin_amdgcn_mfma_f32_16x16x32_f16(Af[m], Bf[cur][n], acc[m][n], 0, 0, 0);
        }
        __builtin_amdgcn_s_setprio(0);
    }

    // ---- store: out[b][O&7][O>>3][h][w] * (2pi/8); full 128-B lines ----
    #pragma unroll
    for (int m = 0; m < 4; ++m) {
        int gh  = h0 + wave * 2 + (m >> 1);
        int gwb = w0 + (m & 1) * 16 + ks4 * 4;
        #pragma unroll
        for (int n = 0; n < 4; ++n) {
            int O = n * 16 + lO;
            float* op = out + (((size_t)(b * 8 + (O & 7)) * 8 + (O >> 3)) << 16)
                            + gh * 256 + gwb;
            *(f32x4*)op = acc[m][n] * PI4_F;
        }
    }
}

// ---- fallback (small ws): round-3 single-kernel conv reading f32 X ----
__global__ __launch_bounds__(512, 4) void conv_kernel_f32(const float* __restrict__ X,
                                                          const __half* __restrict__ ksh,
                                                          float* __restrict__ out) {
    __shared__ uint4 xt[720 * 5];
    int blk = blockIdx.x;
    int b = blk >> 7;
    int rem = blk & 127;
    int h0 = (rem >> 3) << 4;
    int w0 = (rem & 7) << 5;
    int tid = threadIdx.x;
    const float* Xb = X + (size_t)b * 32 * 65536;
    for (int lin = tid; lin < 2880; lin += 512) {
        int slotq = lin / 720;
        int pxi = lin - slotq * 720;
        int r = pxi / 36;
        int c = pxi - r * 36;
        int gh = h0 + r - 2;
        int gw = w0 + c - 2;
        union { __half h[8]; uint4 u; } pk;
        if ((unsigned)gh < 256u && (unsigned)gw < 256u) {
            const float* src = Xb + (size_t)slotq * 8 * 65536 + gh * 256 + gw;
            #pragma unroll
            for (int j = 0; j < 8; ++j) pk.h[j] = __float2half(src[j * 65536]);
        } else {
            pk.u = make_uint4(0u, 0u, 0u, 0u);
        }
        xt[pxi * 5 + slotq] = pk.u;
    }
    __syncthreads();
    int wave = tid >> 6, lane = tid & 63;
    int lO = lane & 15, ks4 = lane >> 4;
    const uint4* ksq = (const uint4*)ksh;
    int bidx = lO * 4 + ks4;
    f32x4 acc[4][4] = {};
    int baseA[4];
    #pragma unroll
    for (int q = 0; q < 4; ++q)
        baseA[q] = ((wave * 2 + (q >> 1)) * 36 + (q & 1) * 16 + lO) * 5 + ks4;
    f16x8 Bf[2][4];
    #pragma unroll
    for (int n = 0; n < 4; ++n)
        Bf[0][n] = __builtin_bit_cast(f16x8, ksq[n * 64 + bidx]);
    #pragma unroll
    for (int t = 0; t < 25; ++t) {
        const int cur = t & 1, nxt = cur ^ 1;
        f16x8 Af[4];
        #pragma unroll
        for (int q = 0; q < 4; ++q)
            Af[q] = __builtin_bit_cast(f16x8, xt[baseA[q] + ((t / 5) * 36 + (t % 5)) * 5]);
        if (t < 24) {
            #pragma unroll
            for (int n = 0; n < 4; ++n)
                Bf[nxt][n] = __builtin_bit_cast(f16x8, ksq[(t + 1) * 256 + n * 64 + bidx]);
        }
        #pragma unroll
        for (int q = 0; q < 4; ++q)
            #pragma unroll
            for (int n = 0; n < 4; ++n)
                acc[q][n] = __builtin_amdgcn_mfma_f32_16x16x32_f16(Af[q], Bf[cur][n], acc[q][n], 0, 0, 0);
    }
    #pragma unroll
    for (int q = 0; q < 4; ++q) {
        int gh = h0 + wave * 2 + (q >> 1);
        int gwb = w0 + (q & 1) * 16 + ks4 * 4;
        #pragma unroll
        for (int n = 0; n < 4; ++n) {
            int O = n * 16 + lO;
            float* op = out + (((size_t)(b * 8 + (O & 7)) * 8 + (O >> 3)) << 16) + gh * 256 + gwb;
            *(f32x4*)op = acc[q][n] * PI4_F;
        }
    }
}

extern "C" void kernel_launch(void* const* d_in, const int* in_sizes, int n_in,
                              void* d_out, int out_size, void* d_ws, size_t ws_size,
                              hipStream_t stream) {
    const float* X = (const float*)d_in[0];       // (8, 4, 8, 256, 256) f32
    const float* w = (const float*)d_in[1];       // (4, 200, 8) f32
    float* outp = (float*)d_out;                  // (8, 8, 8, 256, 256) f32
    char* ws = (char*)d_ws;
    __half* ksh = (__half*)ws;                    // 102.4 KB

    build_ks_kernel<<<200, 256, 0, stream>>>(w, ksh);

    if (ws_size >= XH_OFF + XH_BYTES) {
        __half* Xh = (__half*)(ws + XH_OFF);      // 33.55 MB fp16 HWC
        hwc_kernel<<<8 * 256, 256, 0, stream>>>(X, Xh);
        conv_hwc_kernel<<<8 * 256, 256, 0, stream>>>(Xh, ksh, outp);
    } else {
        conv_kernel_f32<<<8 * 16 * 8, 512, 0, stream>>>(X, ksh, outp);
    }
}